// Round 2
// baseline (935.063 us; speedup 1.0000x reference)
//
#include <hip/hip_runtime.h>
#include <hip/hip_bf16.h>
#include <math.h>

typedef __attribute__((ext_vector_type(4))) float f32x4;
typedef __attribute__((ext_vector_type(8))) __bf16 bf16x8;
typedef __attribute__((ext_vector_type(4))) __bf16 bf16x4;

static constexpr float SCALE = 0.08838834764831845f; // 128^-0.5

__device__ __forceinline__ void load_lds16(const void* g, void* l) {
  __builtin_amdgcn_global_load_lds(
      (const __attribute__((address_space(1))) void*)g,
      (__attribute__((address_space(3))) void*)l, 16, 0, 0);
}

// ---------------- fp32 -> bf16 cast ----------------
__global__ __launch_bounds__(256) void cast_kernel(const float* __restrict__ s,
                                                   __bf16* __restrict__ d, int n4) {
  int i = blockIdx.x * blockDim.x + threadIdx.x;
  int stride = gridDim.x * blockDim.x;
  for (; i < n4; i += stride) {
    float4 v = reinterpret_cast<const float4*>(s)[i];
    bf16x4 o;
    o[0] = (__bf16)v.x; o[1] = (__bf16)v.y; o[2] = (__bf16)v.z; o[3] = (__bf16)v.w;
    reinterpret_cast<bf16x4*>(d)[i] = o;
  }
}

// ---------------- bf16 GEMM: C = A(MxK) * B(NxK)^T + bias ----------------
// EPI: 0 = store bf16, 1 = store bf16 relu, 2 = store f32
template <int EPI>
__global__ __launch_bounds__(256) void gemm_bt(
    const __bf16* __restrict__ A, const __bf16* __restrict__ Bw,
    const float* __restrict__ bvec, __bf16* __restrict__ Cb,
    float* __restrict__ Cf, int M, int N, int K) {
  __shared__ __bf16 As[128 * 64];  // rows of 128B, XOR-swizzled
  __shared__ __bf16 Bs[128 * 64];
  const int ntn = N >> 7;
  const int tm = blockIdx.x / ntn, tn = blockIdx.x % ntn;
  const int t = threadIdx.x, w = t >> 6, lane = t & 63;
  const int wr = (w >> 1) << 6, wc = (w & 1) << 6;
  const int l15 = lane & 15, lq = lane >> 4;

  f32x4 acc[4][4] = {};

  const int srow = lane >> 3;          // row within 8-row chunk
  const int sbo = (lane & 7) << 4;     // physical byte-in-row (128B rows)
  const size_t aBase = (size_t)(tm << 7) * K;
  const size_t bBase = (size_t)(tn << 7) * K;

  for (int kt = 0; kt < K; kt += 64) {
#pragma unroll
    for (int i = 0; i < 4; ++i) {
      int c = (w << 2) + i;
      int r = (c << 3) + srow;
      int ke = ((sbo ^ ((r & 7) << 4)) >> 1) + kt;  // inverse-swizzled source
      load_lds16(A + aBase + (size_t)r * K + ke, (char*)As + (c << 10));
      load_lds16(Bw + bBase + (size_t)r * K + ke, (char*)Bs + (c << 10));
    }
    __syncthreads();
#pragma unroll
    for (int ks = 0; ks < 2; ++ks) {
      bf16x8 af[4], bfv[4];
      const int lb = (ks << 6) + (lq << 4);  // logical byte in 128B row
#pragma unroll
      for (int m = 0; m < 4; ++m) {
        int r = wr + (m << 4) + l15;
        af[m] = *(const bf16x8*)((const char*)As + r * 128 + (lb ^ ((r & 7) << 4)));
      }
#pragma unroll
      for (int n = 0; n < 4; ++n) {
        int r = wc + (n << 4) + l15;
        bfv[n] = *(const bf16x8*)((const char*)Bs + r * 128 + (lb ^ ((r & 7) << 4)));
      }
#pragma unroll
      for (int m = 0; m < 4; ++m)
#pragma unroll
        for (int n = 0; n < 4; ++n)
          acc[m][n] = __builtin_amdgcn_mfma_f32_16x16x32_bf16(af[m], bfv[n], acc[m][n], 0, 0, 0);
    }
    __syncthreads();
  }
  // epilogue: D row=(lane>>4)*4+reg, col=lane&15
  const int row0 = (tm << 7) + wr + (lq << 2);
  const int col0 = (tn << 7) + wc + l15;
#pragma unroll
  for (int n = 0; n < 4; ++n) {
    int col = col0 + (n << 4);
    float bv = bvec[col];
#pragma unroll
    for (int m = 0; m < 4; ++m) {
#pragma unroll
      for (int r = 0; r < 4; ++r) {
        int row = row0 + (m << 4) + r;
        float v = acc[m][n][r] + bv;
        if (EPI == 1) v = fmaxf(v, 0.f);
        if (EPI == 2)
          Cf[(size_t)row * N + col] = v;
        else
          Cb[(size_t)row * N + col] = (__bf16)v;
      }
    }
  }
}

// ---------------- flash attention over flat groups ----------------
// Q,K,V,ctx viewed as [128 groups][1024][128] (contiguous). scores=(QK^T+bias)*scale.
__global__ __launch_bounds__(256) void attn_flash(
    const __bf16* __restrict__ Q, const __bf16* __restrict__ K,
    const __bf16* __restrict__ V, const float* __restrict__ bias,
    __bf16* __restrict__ ctx) {
  __shared__ __bf16 Qs[64 * 128];    // rows 256B, swizzled
  __shared__ __bf16 Ks[64 * 128];    // rows 256B, swizzled
  __shared__ __bf16 VTs[128 * 64];   // [e][k] rows 128B, swizzled
  __shared__ __bf16 Ps[4][16 * 64];  // per-wave P tile, rows 128B, swizzled

  const int g = blockIdx.x >> 4;
  const int q0 = (blockIdx.x & 15) << 6;
  const size_t goff = (size_t)g << 17;
  const __bf16* Qg = Q + goff;
  const __bf16* Kg = K + goff;
  const __bf16* Vg = V + goff;

  const int t = threadIdx.x, w = t >> 6, lane = t & 63;
  const int l15 = lane & 15, lq = lane >> 4;

  // stage Q once (chunks of 1KB = 4 rows of 256B)
  {
    int srow = lane >> 4;
    int sbo = (lane & 15) << 4;
#pragma unroll
    for (int i = 0; i < 4; ++i) {
      int c = (w << 2) + i;
      int r = (c << 2) + srow;
      int ke = (sbo ^ ((r & 7) << 4)) >> 1;
      load_lds16(Qg + (size_t)(q0 + r) * 128 + ke, (char*)Qs + (c << 10));
    }
  }

  float mrun[4], lrun[4];
#pragma unroll
  for (int r = 0; r < 4; ++r) { mrun[r] = -INFINITY; lrun[r] = 0.f; }
  f32x4 cacc[8] = {};

  for (int kb = 0; kb < 1024; kb += 64) {
    // stage K tile
    {
      int srow = lane >> 4;
      int sbo = (lane & 15) << 4;
#pragma unroll
      for (int i = 0; i < 4; ++i) {
        int c = (w << 2) + i;
        int r = (c << 2) + srow;
        int ke = (sbo ^ ((r & 7) << 4)) >> 1;
        load_lds16(Kg + (size_t)(kb + r) * 128 + ke, (char*)Ks + (c << 10));
      }
    }
    // stage V transposed: VTs[e][k]
    {
      int kk = t & 63, eh = t >> 6;
      const __bf16* vs = Vg + (size_t)(kb + kk) * 128 + (eh << 5);
      bf16x8 vv[4];
#pragma unroll
      for (int i = 0; i < 4; ++i) vv[i] = *(const bf16x8*)(vs + (i << 3));
#pragma unroll
      for (int i = 0; i < 4; ++i)
#pragma unroll
        for (int j = 0; j < 8; ++j) {
          int e = (eh << 5) + (i << 3) + j;
          *(__bf16*)((char*)VTs + e * 128 + ((kk << 1) ^ ((e & 7) << 4))) = vv[i][j];
        }
    }
    __syncthreads();

    // scores: wave w owns q rows [w*16, w*16+16), k cols [kb, kb+64)
    f32x4 sacc[4] = {};
#pragma unroll
    for (int ec = 0; ec < 4; ++ec) {
      const int lb = (ec << 6) + (lq << 4);  // logical byte in 256B row
      int ra = (w << 4) + l15;
      bf16x8 af = *(const bf16x8*)((const char*)Qs + ra * 256 + (lb ^ ((ra & 7) << 4)));
#pragma unroll
      for (int n = 0; n < 4; ++n) {
        int rb = (n << 4) + l15;
        bf16x8 bfv = *(const bf16x8*)((const char*)Ks + rb * 256 + (lb ^ ((rb & 7) << 4)));
        sacc[n] = __builtin_amdgcn_mfma_f32_16x16x32_bf16(af, bfv, sacc[n], 0, 0, 0);
      }
    }

    // add bias, scale
    float sv[4][4];
    const int qg0 = q0 + (w << 4) + (lq << 2);
#pragma unroll
    for (int n = 0; n < 4; ++n) {
      int kcol = kb + (n << 4) + l15;
#pragma unroll
      for (int r = 0; r < 4; ++r)
        sv[n][r] = (sacc[n][r] + bias[(size_t)(qg0 + r) * 1024 + kcol]) * SCALE;
    }

    // online softmax (rows live in 16-lane groups)
    float alpha[4], pb[4][4];
#pragma unroll
    for (int r = 0; r < 4; ++r) {
      float mx = fmaxf(fmaxf(sv[0][r], sv[1][r]), fmaxf(sv[2][r], sv[3][r]));
      mx = fmaxf(mx, __shfl_xor(mx, 1));
      mx = fmaxf(mx, __shfl_xor(mx, 2));
      mx = fmaxf(mx, __shfl_xor(mx, 4));
      mx = fmaxf(mx, __shfl_xor(mx, 8));
      float mnew = fmaxf(mrun[r], mx);
      alpha[r] = __expf(mrun[r] - mnew);
      mrun[r] = mnew;
      float ps = 0.f;
#pragma unroll
      for (int n = 0; n < 4; ++n) {
        float p = __expf(sv[n][r] - mnew);
        pb[n][r] = p;
        ps += p;
      }
      ps += __shfl_xor(ps, 1);
      ps += __shfl_xor(ps, 2);
      ps += __shfl_xor(ps, 4);
      ps += __shfl_xor(ps, 8);
      lrun[r] = lrun[r] * alpha[r] + ps;
    }
#pragma unroll
    for (int et = 0; et < 8; ++et)
#pragma unroll
      for (int r = 0; r < 4; ++r) cacc[et][r] *= alpha[r];

    // P -> LDS (bf16, swizzled rows of 128B)
#pragma unroll
    for (int n = 0; n < 4; ++n)
#pragma unroll
      for (int r = 0; r < 4; ++r) {
        int row = (lq << 2) + r;
        int cb2 = ((n << 4) + l15) << 1;
        *(__bf16*)((char*)Ps[w] + row * 128 + (cb2 ^ ((row & 7) << 4))) = (__bf16)pb[n][r];
      }
    asm volatile("s_waitcnt lgkmcnt(0)" ::: "memory");
    __builtin_amdgcn_sched_barrier(0);

    // PV: ctx += P * V
#pragma unroll
    for (int ks = 0; ks < 2; ++ks) {
      const int lb = (ks << 6) + (lq << 4);
      int rp = l15;
      bf16x8 paf = *(const bf16x8*)((const char*)Ps[w] + rp * 128 + (lb ^ ((rp & 7) << 4)));
#pragma unroll
      for (int et = 0; et < 8; ++et) {
        int e = (et << 4) + l15;
        bf16x8 vf = *(const bf16x8*)((const char*)VTs + e * 128 + (lb ^ ((e & 7) << 4)));
        cacc[et] = __builtin_amdgcn_mfma_f32_16x16x32_bf16(paf, vf, cacc[et], 0, 0, 0);
      }
    }
    __syncthreads();
  }

  // finalize: divide by row sums, store bf16
  __bf16* cg = ctx + goff;
  const int qr = q0 + (w << 4) + (lq << 2);
#pragma unroll
  for (int et = 0; et < 8; ++et)
#pragma unroll
    for (int r = 0; r < 4; ++r) {
      float v = cacc[et][r] / lrun[r];
      cg[(size_t)(qr + r) * 128 + (et << 4) + l15] = (__bf16)v;
    }
}

// ---------------- attn[0] full softmax matrix (group 0) ----------------
__global__ __launch_bounds__(256) void attn_head0(
    const __bf16* __restrict__ Q, const __bf16* __restrict__ K,
    const float* __restrict__ bias, float* __restrict__ out) {
  __shared__ float qrow[128];
  __shared__ float red[8];
  const int q = blockIdx.x, t = threadIdx.x;
  if (t < 128) qrow[t] = (float)Q[(size_t)q * 128 + t];
  __syncthreads();
  float s[4];
#pragma unroll
  for (int c = 0; c < 4; ++c) {
    int kc = (c << 8) + t;
    const __bf16* kr = K + (size_t)kc * 128;
    float dot = 0.f;
#pragma unroll
    for (int e = 0; e < 128; e += 8) {
      bf16x8 kv = *(const bf16x8*)(kr + e);
#pragma unroll
      for (int j = 0; j < 8; ++j) dot += qrow[e + j] * (float)kv[j];
    }
    s[c] = (dot + bias[(size_t)q * 1024 + kc]) * SCALE;
  }
  float mx = fmaxf(fmaxf(s[0], s[1]), fmaxf(s[2], s[3]));
#pragma unroll
  for (int d = 32; d >= 1; d >>= 1) mx = fmaxf(mx, __shfl_xor(mx, d));
  const int w = t >> 6, lane = t & 63;
  if (lane == 0) red[w] = mx;
  __syncthreads();
  mx = fmaxf(fmaxf(red[0], red[1]), fmaxf(red[2], red[3]));
  float ex[4], sum = 0.f;
#pragma unroll
  for (int c = 0; c < 4; ++c) { ex[c] = __expf(s[c] - mx); sum += ex[c]; }
#pragma unroll
  for (int d = 32; d >= 1; d >>= 1) sum += __shfl_xor(sum, d);
  __syncthreads();
  if (lane == 0) red[4 + w] = sum;
  __syncthreads();
  sum = red[4] + red[5] + red[6] + red[7];
  float inv = 1.f / sum;
#pragma unroll
  for (int c = 0; c < 4; ++c) out[(size_t)q * 1024 + (c << 8) + t] = ex[c] * inv;
}

// ---------------- LayerNorm(a + b) * g + beta ----------------
// a is f32; b is f32 (B_BF16=0) or bf16 (B_BF16=1). outf/outb optional.
template <int B_BF16>
__global__ __launch_bounds__(256) void ln_res(
    const float* __restrict__ a, const void* __restrict__ bptr,
    const float* __restrict__ gam, const float* __restrict__ bet,
    float* __restrict__ outf, __bf16* __restrict__ outb) {
  __shared__ float red[8];
  const int row = blockIdx.x, t = threadIdx.x;
  const size_t base = (size_t)row << 10;
  float4 va = reinterpret_cast<const float4*>(a + base)[t];
  float b0, b1, b2, b3;
  if (B_BF16) {
    bf16x4 vb = reinterpret_cast<const bf16x4*>((const __bf16*)bptr + base)[t];
    b0 = (float)vb[0]; b1 = (float)vb[1]; b2 = (float)vb[2]; b3 = (float)vb[3];
  } else {
    float4 vb = reinterpret_cast<const float4*>((const float*)bptr + base)[t];
    b0 = vb.x; b1 = vb.y; b2 = vb.z; b3 = vb.w;
  }
  float v0 = va.x + b0, v1 = va.y + b1, v2 = va.z + b2, v3 = va.w + b3;
  float s = v0 + v1 + v2 + v3;
  float qq = v0 * v0 + v1 * v1 + v2 * v2 + v3 * v3;
#pragma unroll
  for (int d = 32; d >= 1; d >>= 1) {
    s += __shfl_xor(s, d);
    qq += __shfl_xor(qq, d);
  }
  const int w = t >> 6, lane = t & 63;
  if (lane == 0) { red[w] = s; red[4 + w] = qq; }
  __syncthreads();
  s = red[0] + red[1] + red[2] + red[3];
  qq = red[4] + red[5] + red[6] + red[7];
  const float mu = s * (1.f / 1024.f);
  const float var = qq * (1.f / 1024.f) - mu * mu;
  const float rs = rsqrtf(var + 1e-5f);
  float4 g4 = reinterpret_cast<const float4*>(gam)[t];
  float4 b4 = reinterpret_cast<const float4*>(bet)[t];
  float o0 = (v0 - mu) * rs * g4.x + b4.x;
  float o1 = (v1 - mu) * rs * g4.y + b4.y;
  float o2 = (v2 - mu) * rs * g4.z + b4.z;
  float o3 = (v3 - mu) * rs * g4.w + b4.w;
  if (outf) reinterpret_cast<float4*>(outf + base)[t] = make_float4(o0, o1, o2, o3);
  if (outb) {
    bf16x4 ob;
    ob[0] = (__bf16)o0; ob[1] = (__bf16)o1; ob[2] = (__bf16)o2; ob[3] = (__bf16)o3;
    reinterpret_cast<bf16x4*>(outb + base)[t] = ob;
  }
}

extern "C" void kernel_launch(void* const* d_in, const int* in_sizes, int n_in,
                              void* d_out, int out_size, void* d_ws, size_t ws_size,
                              hipStream_t stream) {
  (void)in_sizes; (void)n_in; (void)out_size; (void)ws_size;
  const float* x    = (const float*)d_in[0];
  const float* bias = (const float*)d_in[1];
  const float* Wq   = (const float*)d_in[2];
  const float* bq   = (const float*)d_in[3];
  const float* Wk   = (const float*)d_in[4];
  const float* bk   = (const float*)d_in[5];
  const float* Wv   = (const float*)d_in[6];
  const float* bv   = (const float*)d_in[7];
  const float* Wo   = (const float*)d_in[8];
  const float* bo   = (const float*)d_in[9];
  const float* g1   = (const float*)d_in[10];
  const float* b1l  = (const float*)d_in[11];
  const float* W1   = (const float*)d_in[12];
  const float* b1f  = (const float*)d_in[13];
  const float* W2   = (const float*)d_in[14];
  const float* b2f  = (const float*)d_in[15];
  const float* g2   = (const float*)d_in[16];
  const float* b2l  = (const float*)d_in[17];

  // ---- workspace layout (184 MB total) ----
  char* ws = (char*)d_ws;
  size_t off = 0;
  auto alloc = [&](size_t bytes) {
    char* p = ws + off;
    off += (bytes + 255) & ~(size_t)255;
    return p;
  };
  __bf16* wqb  = (__bf16*)alloc(2097152);
  __bf16* wkb  = (__bf16*)alloc(2097152);
  __bf16* wvb  = (__bf16*)alloc(2097152);
  __bf16* wob  = (__bf16*)alloc(2097152);
  __bf16* w1b  = (__bf16*)alloc(8388608);
  __bf16* w2b  = (__bf16*)alloc(8388608);
  __bf16* xb   = (__bf16*)alloc(33554432);        // x bf16; later res1 bf16
  __bf16* Qb   = (__bf16*)alloc(4ull * 33554432); // Q,K,V,ctx; later h [16384,4096]
  __bf16* Kb   = Qb + 16777216;
  __bf16* Vb   = Kb + 16777216;
  __bf16* ctxb = Vb + 16777216;
  __bf16* hb   = Qb;
  __bf16* res1b = xb;

  // d_out doubles as f32 scratch for attn_out / ff (out2 slot, overwritten at end)
  float* out2     = (float*)d_out;
  float* selfattn = (float*)d_out + 16777216;
  float* attn_out = out2;
  float* ff       = out2;

  // casts
  cast_kernel<<<2048, 256, 0, stream>>>(x, xb, 16777216 / 4);
  cast_kernel<<<1024, 256, 0, stream>>>(Wq, wqb, 1048576 / 4);
  cast_kernel<<<1024, 256, 0, stream>>>(Wk, wkb, 1048576 / 4);
  cast_kernel<<<1024, 256, 0, stream>>>(Wv, wvb, 1048576 / 4);
  cast_kernel<<<1024, 256, 0, stream>>>(Wo, wob, 1048576 / 4);
  cast_kernel<<<1024, 256, 0, stream>>>(W1, w1b, 4194304 / 4);
  cast_kernel<<<1024, 256, 0, stream>>>(W2, w2b, 4194304 / 4);

  // QKV projections
  gemm_bt<0><<<128 * 8, 256, 0, stream>>>(xb, wqb, bq, Qb, nullptr, 16384, 1024, 1024);
  gemm_bt<0><<<128 * 8, 256, 0, stream>>>(xb, wkb, bk, Kb, nullptr, 16384, 1024, 1024);
  gemm_bt<0><<<128 * 8, 256, 0, stream>>>(xb, wvb, bv, Vb, nullptr, 16384, 1024, 1024);

  // attention (head0 matrix first; then flash)
  attn_head0<<<1024, 256, 0, stream>>>(Qb, Kb, bias, selfattn);
  attn_flash<<<128 * 16, 256, 0, stream>>>(Qb, Kb, Vb, bias, ctxb);

  // output projection -> f32 scratch in d_out
  gemm_bt<2><<<128 * 8, 256, 0, stream>>>(ctxb, wob, bo, nullptr, attn_out, 16384, 1024, 1024);

  // ln1(attn_out + x) -> res1 bf16 (xb slot)
  ln_res<0><<<16384, 256, 0, stream>>>(attn_out, x, g1, b1l, nullptr, res1b);

  // FFN
  gemm_bt<1><<<128 * 32, 256, 0, stream>>>(res1b, w1b, b1f, hb, nullptr, 16384, 4096, 1024);
  gemm_bt<2><<<128 * 8, 256, 0, stream>>>(hb, w2b, b2f, nullptr, ff, 16384, 1024, 4096);

  // ln2(ff + res1) -> out2 (in-place over ff)
  ln_res<1><<<16384, 256, 0, stream>>>(ff, res1b, g2, b2l, out2, nullptr);
}

// Round 3
// 893.864 us; speedup vs baseline: 1.0461x; 1.0461x over previous
//
#include <hip/hip_runtime.h>
#include <hip/hip_bf16.h>
#include <math.h>

typedef __attribute__((ext_vector_type(4))) float f32x4;
typedef __attribute__((ext_vector_type(8))) __bf16 bf16x8;
typedef __attribute__((ext_vector_type(4))) __bf16 bf16x4;

static constexpr float SCALE = 0.08838834764831845f; // 128^-0.5

__device__ __forceinline__ void load_lds16(const void* g, void* l) {
  __builtin_amdgcn_global_load_lds(
      (const __attribute__((address_space(1))) void*)g,
      (__attribute__((address_space(3))) void*)l, 16, 0, 0);
}

// ---------------- fp32 -> bf16 cast ----------------
__global__ __launch_bounds__(256) void cast_kernel(const float* __restrict__ s,
                                                   __bf16* __restrict__ d, int n4) {
  int i = blockIdx.x * blockDim.x + threadIdx.x;
  int stride = gridDim.x * blockDim.x;
  for (; i < n4; i += stride) {
    float4 v = reinterpret_cast<const float4*>(s)[i];
    bf16x4 o;
    o[0] = (__bf16)v.x; o[1] = (__bf16)v.y; o[2] = (__bf16)v.z; o[3] = (__bf16)v.w;
    reinterpret_cast<bf16x4*>(d)[i] = o;
  }
}

// ---------------- bias transpose: dst[k][q] = (bf16)src[q][k] ----------------
__global__ __launch_bounds__(256) void transpose_bias(const float* __restrict__ src,
                                                      __bf16* __restrict__ dst) {
  __shared__ float tile[64][65];
  const int bx = blockIdx.x & 15;   // col tile
  const int by = blockIdx.x >> 4;   // row tile
  const int t = threadIdx.x;
  const int lx = t & 63, ly = t >> 6;
#pragma unroll
  for (int i = 0; i < 16; ++i) {
    int row = (ly << 4) + i;
    tile[row][lx] = src[(size_t)(by * 64 + row) * 1024 + bx * 64 + lx];
  }
  __syncthreads();
#pragma unroll
  for (int i = 0; i < 16; ++i) {
    int row = (ly << 4) + i;
    dst[(size_t)(bx * 64 + row) * 1024 + by * 64 + lx] = (__bf16)tile[lx][row];
  }
}

// ---------------- bf16 GEMM: C = A(MxK) * B(NxK)^T + bias ----------------
// EPI: 0 = store bf16, 1 = store bf16 relu, 2 = store f32,
//      3 = store bf16 transposed-per-group (for V: VT[g][dh][s'])
template <int EPI>
__global__ __launch_bounds__(256) void gemm_bt(
    const __bf16* __restrict__ A, const __bf16* __restrict__ Bw,
    const float* __restrict__ bvec, __bf16* __restrict__ Cb,
    float* __restrict__ Cf, int M, int N, int K) {
  __shared__ __bf16 As[128 * 64];  // rows of 128B, XOR-swizzled
  __shared__ __bf16 Bs[128 * 64];
  const int ntn = N >> 7;
  // bijective XCD swizzle (grid is always a multiple of 8 here)
  const int nwg = gridDim.x;
  const int bid = blockIdx.x;
  const int b = (bid & 7) * (nwg >> 3) + (bid >> 3);
  const int tm = b / ntn, tn = b % ntn;
  const int t = threadIdx.x, w = t >> 6, lane = t & 63;
  const int wr = (w >> 1) << 6, wc = (w & 1) << 6;
  const int l15 = lane & 15, lq = lane >> 4;

  f32x4 acc[4][4] = {};

  const int srow = lane >> 3;          // row within 8-row chunk
  const int sbo = (lane & 7) << 4;     // physical byte-in-row (128B rows)
  const size_t aBase = (size_t)(tm << 7) * K;
  const size_t bBase = (size_t)(tn << 7) * K;

  for (int kt = 0; kt < K; kt += 64) {
#pragma unroll
    for (int i = 0; i < 4; ++i) {
      int c = (w << 2) + i;
      int r = (c << 3) + srow;
      int ke = ((sbo ^ ((r & 7) << 4)) >> 1) + kt;  // inverse-swizzled source
      load_lds16(A + aBase + (size_t)r * K + ke, (char*)As + (c << 10));
      load_lds16(Bw + bBase + (size_t)r * K + ke, (char*)Bs + (c << 10));
    }
    __syncthreads();
#pragma unroll
    for (int ks = 0; ks < 2; ++ks) {
      bf16x8 af[4], bfv[4];
      const int lb = (ks << 6) + (lq << 4);  // logical byte in 128B row
#pragma unroll
      for (int m = 0; m < 4; ++m) {
        int r = wr + (m << 4) + l15;
        af[m] = *(const bf16x8*)((const char*)As + r * 128 + (lb ^ ((r & 7) << 4)));
      }
#pragma unroll
      for (int n = 0; n < 4; ++n) {
        int r = wc + (n << 4) + l15;
        bfv[n] = *(const bf16x8*)((const char*)Bs + r * 128 + (lb ^ ((r & 7) << 4)));
      }
#pragma unroll
      for (int m = 0; m < 4; ++m)
#pragma unroll
        for (int n = 0; n < 4; ++n)
          acc[m][n] = __builtin_amdgcn_mfma_f32_16x16x32_bf16(af[m], bfv[n], acc[m][n], 0, 0, 0);
    }
    __syncthreads();
  }
  // epilogue: D row=(lane>>4)*4+reg, col=lane&15
  const int row0 = (tm << 7) + wr + (lq << 2);
  const int col0 = (tn << 7) + wc + l15;
#pragma unroll
  for (int n = 0; n < 4; ++n) {
    int col = col0 + (n << 4);
    float bv = bvec[col];
#pragma unroll
    for (int m = 0; m < 4; ++m) {
#pragma unroll
      for (int r = 0; r < 4; ++r) {
        int row = row0 + (m << 4) + r;
        float v = acc[m][n][r] + bv;
        if (EPI == 1) v = fmaxf(v, 0.f);
        if (EPI == 2) {
          Cf[(size_t)row * N + col] = v;
        } else if (EPI == 3) {
          // VT[g= row>>7][dh= col&127][s' = (row&127)*8 + (col>>7)]
          size_t vt = ((size_t)(row >> 7) << 17) + ((size_t)(col & 127) << 10) +
                      ((row & 127) << 3) + (col >> 7);
          Cb[vt] = (__bf16)v;
        } else {
          Cb[(size_t)row * N + col] = (__bf16)v;
        }
      }
    }
  }
}

// ---------------- flash attention over flat groups ----------------
// Q,K viewed as [128][1024][128]; VT as [128][128 e][1024 k]; biasT[k][q] bf16.
// Swapped QK^T: S^T = mfma(K, Q) so each lane owns one q-row (q = lane&15).
__global__ __launch_bounds__(256) void attn_flash(
    const __bf16* __restrict__ Q, const __bf16* __restrict__ K,
    const __bf16* __restrict__ VT, const __bf16* __restrict__ biasT,
    __bf16* __restrict__ ctx) {
  __shared__ __bf16 Qs[64 * 128];    // rows 256B, swizzled
  __shared__ __bf16 Ks[64 * 128];    // rows 256B, swizzled
  __shared__ __bf16 VTs[128 * 64];   // [e][k-chunk] rows 128B, swizzled
  __shared__ __bf16 Ps[4][16 * 64];  // per-wave P tile, rows 128B, swizzled

  // XCD swizzle: 16 q-blocks of the same group land on the same XCD
  const int bid = blockIdx.x;
  const int b = ((bid & 7) << 8) | (bid >> 3);
  const int g = b >> 4;
  const int q0 = (b & 15) << 6;
  const size_t goff = (size_t)g << 17;
  const __bf16* Qg = Q + goff;
  const __bf16* Kg = K + goff;
  const __bf16* VTg = VT + goff;

  const int t = threadIdx.x, w = t >> 6, lane = t & 63;
  const int l15 = lane & 15, lq = lane >> 4;

  // stage Q once (chunks of 1KB = 4 rows of 256B)
  {
    int srow = lane >> 4;
    int sbo = (lane & 15) << 4;
#pragma unroll
    for (int i = 0; i < 4; ++i) {
      int c = (w << 2) + i;
      int r = (c << 2) + srow;
      int ke = (sbo ^ ((r & 7) << 4)) >> 1;
      load_lds16(Qg + (size_t)(q0 + r) * 128 + ke, (char*)Qs + (c << 10));
    }
  }

  float mrun = -INFINITY, lrun = 0.f;
  f32x4 cacc[8] = {};
  bf16x8 qf[4];
  const int qg = q0 + (w << 4) + l15;  // this lane's q-row (global within group)
  const int ra = (w << 4) + l15;       // q-row within Qs

  for (int kb = 0; kb < 1024; kb += 64) {
    // stage K tile (4 rows of 256B per 1KB chunk)
    {
      int srow = lane >> 4;
      int sbo = (lane & 15) << 4;
#pragma unroll
      for (int i = 0; i < 4; ++i) {
        int c = (w << 2) + i;
        int r = (c << 2) + srow;
        int ke = (sbo ^ ((r & 7) << 4)) >> 1;
        load_lds16(Kg + (size_t)(kb + r) * 128 + ke, (char*)Ks + (c << 10));
      }
    }
    // stage VT tile (8 rows of 128B per 1KB chunk): VTs[e][0..63] = VTg[e][kb..kb+64]
    {
      int srow = lane >> 3;
      int sbo = (lane & 7) << 4;
#pragma unroll
      for (int i = 0; i < 4; ++i) {
        int c = (w << 2) + i;
        int e = (c << 3) + srow;
        int ke = kb + ((sbo ^ ((e & 7) << 4)) >> 1);
        load_lds16(VTg + (size_t)e * 1024 + ke, (char*)VTs + (c << 10));
      }
    }
    __syncthreads();

    if (kb == 0) {
#pragma unroll
      for (int ec = 0; ec < 4; ++ec) {
        int lb = (ec << 6) + (lq << 4);
        qf[ec] = *(const bf16x8*)((const char*)Qs + ra * 256 + (lb ^ ((ra & 7) << 4)));
      }
    }

    // S^T = K * Q^T : sacc[kn] is D[16k x 16q], lane holds k=kn*16+lq*4+r, q=l15
    f32x4 sacc[4] = {};
#pragma unroll
    for (int ec = 0; ec < 4; ++ec) {
      const int lb = (ec << 6) + (lq << 4);
#pragma unroll
      for (int kn = 0; kn < 4; ++kn) {
        int rb = (kn << 4) + l15;
        bf16x8 kf = *(const bf16x8*)((const char*)Ks + rb * 256 + (lb ^ ((rb & 7) << 4)));
        sacc[kn] = __builtin_amdgcn_mfma_f32_16x16x32_bf16(kf, qf[ec], sacc[kn], 0, 0, 0);
      }
    }

    // bias (transposed, coalesced in q) + scale; per-lane softmax over 16 k-values
    float sv[4][4];
#pragma unroll
    for (int kn = 0; kn < 4; ++kn) {
      int kbase = kb + (kn << 4) + (lq << 2);
#pragma unroll
      for (int r = 0; r < 4; ++r)
        sv[kn][r] = (sacc[kn][r] + (float)biasT[((size_t)(kbase + r) << 10) + qg]) * SCALE;
    }
    float mt = sv[0][0];
#pragma unroll
    for (int kn = 0; kn < 4; ++kn)
#pragma unroll
      for (int r = 0; r < 4; ++r) mt = fmaxf(mt, sv[kn][r]);
    mt = fmaxf(mt, __shfl_xor(mt, 16));
    mt = fmaxf(mt, __shfl_xor(mt, 32));
    float mnew = fmaxf(mrun, mt);
    float alpha = __expf(mrun - mnew);
    mrun = mnew;
    float psum = 0.f;
#pragma unroll
    for (int kn = 0; kn < 4; ++kn)
#pragma unroll
      for (int r = 0; r < 4; ++r) {
        float p = __expf(sv[kn][r] - mnew);
        sv[kn][r] = p;
        psum += p;
      }
    psum += __shfl_xor(psum, 16);
    psum += __shfl_xor(psum, 32);
    lrun = lrun * alpha + psum;

    // redistribute alpha to PV-row owners (PV D-row = lq*4+r, state lives at l15=q)
    float alphaR[4];
#pragma unroll
    for (int r = 0; r < 4; ++r)
      alphaR[r] = __shfl(alpha, (lane & 48) + ((lane & 48) >> 2) + r);
#pragma unroll
    for (int et = 0; et < 8; ++et)
#pragma unroll
      for (int r = 0; r < 4; ++r) cacc[et][r] *= alphaR[r];

    // pack P rows (4 consecutive k per lane) -> Ps[w][q=l15][k], 8B writes
#pragma unroll
    for (int kn = 0; kn < 4; ++kn) {
      bf16x4 pk;
      pk[0] = (__bf16)sv[kn][0]; pk[1] = (__bf16)sv[kn][1];
      pk[2] = (__bf16)sv[kn][2]; pk[3] = (__bf16)sv[kn][3];
      int bo = (kn << 5) + (lq << 3);
      *(bf16x4*)((char*)Ps[w] + l15 * 128 + (bo ^ ((l15 & 7) << 4))) = pk;
    }
    asm volatile("s_waitcnt lgkmcnt(0)" ::: "memory");
    __builtin_amdgcn_sched_barrier(0);

    // PV: D[q=lq*4+r][e=l15]; A = P (row q=l15 frag), B = VT (row e frag)
#pragma unroll
    for (int ks = 0; ks < 2; ++ks) {
      const int lb = (ks << 6) + (lq << 4);
      bf16x8 paf = *(const bf16x8*)((const char*)Ps[w] + l15 * 128 + (lb ^ ((l15 & 7) << 4)));
#pragma unroll
      for (int et = 0; et < 8; ++et) {
        int e = (et << 4) + l15;
        bf16x8 vf = *(const bf16x8*)((const char*)VTs + e * 128 + (lb ^ ((e & 7) << 4)));
        cacc[et] = __builtin_amdgcn_mfma_f32_16x16x32_bf16(paf, vf, cacc[et], 0, 0, 0);
      }
    }
    __syncthreads();
  }

  // finalize: divide by row sums (gathered from row-owner lanes), store bf16
  float lrunR[4];
#pragma unroll
  for (int r = 0; r < 4; ++r)
    lrunR[r] = __shfl(lrun, (lane & 48) + ((lane & 48) >> 2) + r);
  __bf16* cg = ctx + goff;
  const int qr = q0 + (w << 4) + (lq << 2);
#pragma unroll
  for (int et = 0; et < 8; ++et)
#pragma unroll
    for (int r = 0; r < 4; ++r) {
      float v = cacc[et][r] / lrunR[r];
      cg[(size_t)(qr + r) * 128 + (et << 4) + l15] = (__bf16)v;
    }
}

// ---------------- attn[0] full softmax matrix (group 0) ----------------
__global__ __launch_bounds__(256) void attn_head0(
    const __bf16* __restrict__ Q, const __bf16* __restrict__ K,
    const float* __restrict__ bias, float* __restrict__ out) {
  __shared__ float qrow[128];
  __shared__ float red[8];
  const int q = blockIdx.x, t = threadIdx.x;
  if (t < 128) qrow[t] = (float)Q[(size_t)q * 128 + t];
  __syncthreads();
  float s[4];
#pragma unroll
  for (int c = 0; c < 4; ++c) {
    int kc = (c << 8) + t;
    const __bf16* kr = K + (size_t)kc * 128;
    float dot = 0.f;
#pragma unroll
    for (int e = 0; e < 128; e += 8) {
      bf16x8 kv = *(const bf16x8*)(kr + e);
#pragma unroll
      for (int j = 0; j < 8; ++j) dot += qrow[e + j] * (float)kv[j];
    }
    s[c] = (dot + bias[(size_t)q * 1024 + kc]) * SCALE;
  }
  float mx = fmaxf(fmaxf(s[0], s[1]), fmaxf(s[2], s[3]));
#pragma unroll
  for (int d = 32; d >= 1; d >>= 1) mx = fmaxf(mx, __shfl_xor(mx, d));
  const int w = t >> 6, lane = t & 63;
  if (lane == 0) red[w] = mx;
  __syncthreads();
  mx = fmaxf(fmaxf(red[0], red[1]), fmaxf(red[2], red[3]));
  float ex[4], sum = 0.f;
#pragma unroll
  for (int c = 0; c < 4; ++c) { ex[c] = __expf(s[c] - mx); sum += ex[c]; }
#pragma unroll
  for (int d = 32; d >= 1; d >>= 1) sum += __shfl_xor(sum, d);
  __syncthreads();
  if (lane == 0) red[4 + w] = sum;
  __syncthreads();
  sum = red[4] + red[5] + red[6] + red[7];
  float inv = 1.f / sum;
#pragma unroll
  for (int c = 0; c < 4; ++c) out[(size_t)q * 1024 + (c << 8) + t] = ex[c] * inv;
}

// ---------------- LayerNorm(a + b) * g + beta ----------------
template <int B_BF16>
__global__ __launch_bounds__(256) void ln_res(
    const float* __restrict__ a, const void* __restrict__ bptr,
    const float* __restrict__ gam, const float* __restrict__ bet,
    float* __restrict__ outf, __bf16* __restrict__ outb) {
  __shared__ float red[8];
  const int row = blockIdx.x, t = threadIdx.x;
  const size_t base = (size_t)row << 10;
  float4 va = reinterpret_cast<const float4*>(a + base)[t];
  float b0, b1, b2, b3;
  if (B_BF16) {
    bf16x4 vb = reinterpret_cast<const bf16x4*>((const __bf16*)bptr + base)[t];
    b0 = (float)vb[0]; b1 = (float)vb[1]; b2 = (float)vb[2]; b3 = (float)vb[3];
  } else {
    float4 vb = reinterpret_cast<const float4*>((const float*)bptr + base)[t];
    b0 = vb.x; b1 = vb.y; b2 = vb.z; b3 = vb.w;
  }
  float v0 = va.x + b0, v1 = va.y + b1, v2 = va.z + b2, v3 = va.w + b3;
  float s = v0 + v1 + v2 + v3;
  float qq = v0 * v0 + v1 * v1 + v2 * v2 + v3 * v3;
#pragma unroll
  for (int d = 32; d >= 1; d >>= 1) {
    s += __shfl_xor(s, d);
    qq += __shfl_xor(qq, d);
  }
  const int w = t >> 6, lane = t & 63;
  if (lane == 0) { red[w] = s; red[4 + w] = qq; }
  __syncthreads();
  s = red[0] + red[1] + red[2] + red[3];
  qq = red[4] + red[5] + red[6] + red[7];
  const float mu = s * (1.f / 1024.f);
  const float var = qq * (1.f / 1024.f) - mu * mu;
  const float rs = rsqrtf(var + 1e-5f);
  float4 g4 = reinterpret_cast<const float4*>(gam)[t];
  float4 b4 = reinterpret_cast<const float4*>(bet)[t];
  float o0 = (v0 - mu) * rs * g4.x + b4.x;
  float o1 = (v1 - mu) * rs * g4.y + b4.y;
  float o2 = (v2 - mu) * rs * g4.z + b4.z;
  float o3 = (v3 - mu) * rs * g4.w + b4.w;
  if (outf) reinterpret_cast<float4*>(outf + base)[t] = make_float4(o0, o1, o2, o3);
  if (outb) {
    bf16x4 ob;
    ob[0] = (__bf16)o0; ob[1] = (__bf16)o1; ob[2] = (__bf16)o2; ob[3] = (__bf16)o3;
    reinterpret_cast<bf16x4*>(outb + base)[t] = ob;
  }
}

extern "C" void kernel_launch(void* const* d_in, const int* in_sizes, int n_in,
                              void* d_out, int out_size, void* d_ws, size_t ws_size,
                              hipStream_t stream) {
  (void)in_sizes; (void)n_in; (void)out_size; (void)ws_size;
  const float* x    = (const float*)d_in[0];
  const float* bias = (const float*)d_in[1];
  const float* Wq   = (const float*)d_in[2];
  const float* bq   = (const float*)d_in[3];
  const float* Wk   = (const float*)d_in[4];
  const float* bk   = (const float*)d_in[5];
  const float* Wv   = (const float*)d_in[6];
  const float* bv   = (const float*)d_in[7];
  const float* Wo   = (const float*)d_in[8];
  const float* bo   = (const float*)d_in[9];
  const float* g1   = (const float*)d_in[10];
  const float* b1l  = (const float*)d_in[11];
  const float* W1   = (const float*)d_in[12];
  const float* b1f  = (const float*)d_in[13];
  const float* W2   = (const float*)d_in[14];
  const float* b2f  = (const float*)d_in[15];
  const float* g2   = (const float*)d_in[16];
  const float* b2l  = (const float*)d_in[17];

  // ---- workspace layout (~186 MB) ----
  char* ws = (char*)d_ws;
  size_t off = 0;
  auto alloc = [&](size_t bytes) {
    char* p = ws + off;
    off += (bytes + 255) & ~(size_t)255;
    return p;
  };
  __bf16* wqb  = (__bf16*)alloc(2097152);
  __bf16* wkb  = (__bf16*)alloc(2097152);
  __bf16* wvb  = (__bf16*)alloc(2097152);
  __bf16* wob  = (__bf16*)alloc(2097152);
  __bf16* w1b  = (__bf16*)alloc(8388608);
  __bf16* w2b  = (__bf16*)alloc(8388608);
  __bf16* biasTb = (__bf16*)alloc(2097152);       // bias^T bf16 [k][q]
  __bf16* xb   = (__bf16*)alloc(33554432);        // x bf16; later res1 bf16
  __bf16* Qb   = (__bf16*)alloc(4ull * 33554432); // Q,K,VT,ctx; later h [16384,4096]
  __bf16* Kb   = Qb + 16777216;
  __bf16* VTb  = Kb + 16777216;                   // V stored transposed per group
  __bf16* ctxb = VTb + 16777216;
  __bf16* hb   = Qb;
  __bf16* res1b = xb;

  // d_out doubles as f32 scratch for attn_out / ff (out2 slot, overwritten at end)
  float* out2     = (float*)d_out;
  float* selfattn = (float*)d_out + 16777216;
  float* attn_out = out2;
  float* ff       = out2;

  // casts + bias transpose
  cast_kernel<<<2048, 256, 0, stream>>>(x, xb, 16777216 / 4);
  cast_kernel<<<1024, 256, 0, stream>>>(Wq, wqb, 1048576 / 4);
  cast_kernel<<<1024, 256, 0, stream>>>(Wk, wkb, 1048576 / 4);
  cast_kernel<<<1024, 256, 0, stream>>>(Wv, wvb, 1048576 / 4);
  cast_kernel<<<1024, 256, 0, stream>>>(Wo, wob, 1048576 / 4);
  cast_kernel<<<1024, 256, 0, stream>>>(W1, w1b, 4194304 / 4);
  cast_kernel<<<1024, 256, 0, stream>>>(W2, w2b, 4194304 / 4);
  transpose_bias<<<256, 256, 0, stream>>>(bias, biasTb);

  // QKV projections (V written pre-transposed per group)
  gemm_bt<0><<<128 * 8, 256, 0, stream>>>(xb, wqb, bq, Qb, nullptr, 16384, 1024, 1024);
  gemm_bt<0><<<128 * 8, 256, 0, stream>>>(xb, wkb, bk, Kb, nullptr, 16384, 1024, 1024);
  gemm_bt<3><<<128 * 8, 256, 0, stream>>>(xb, wvb, bv, VTb, nullptr, 16384, 1024, 1024);

  // attention
  attn_head0<<<1024, 256, 0, stream>>>(Qb, Kb, bias, selfattn);
  attn_flash<<<128 * 16, 256, 0, stream>>>(Qb, Kb, VTb, biasTb, ctxb);

  // output projection -> f32 scratch in d_out
  gemm_bt<2><<<128 * 8, 256, 0, stream>>>(ctxb, wob, bo, nullptr, attn_out, 16384, 1024, 1024);

  // ln1(attn_out + x) -> res1 bf16 (xb slot)
  ln_res<0><<<16384, 256, 0, stream>>>(attn_out, x, g1, b1l, nullptr, res1b);

  // FFN
  gemm_bt<1><<<128 * 32, 256, 0, stream>>>(res1b, w1b, b1f, hb, nullptr, 16384, 4096, 1024);
  gemm_bt<2><<<128 * 8, 256, 0, stream>>>(hb, w2b, b2f, nullptr, ff, 16384, 1024, 4096);

  // ln2(ff + res1) -> out2 (in-place over ff)
  ln_res<1><<<16384, 256, 0, stream>>>(ff, res1b, g2, b2l, out2, nullptr);
}

// Round 4
// 868.406 us; speedup vs baseline: 1.0768x; 1.0293x over previous
//
#include <hip/hip_runtime.h>
#include <hip/hip_bf16.h>
#include <math.h>

typedef __attribute__((ext_vector_type(4))) float f32x4;
typedef __attribute__((ext_vector_type(8))) __bf16 bf16x8;
typedef __attribute__((ext_vector_type(4))) __bf16 bf16x4;

static constexpr float SCALE = 0.08838834764831845f; // 128^-0.5

__device__ __forceinline__ void load_lds16(const void* g, void* l) {
  __builtin_amdgcn_global_load_lds(
      (const __attribute__((address_space(1))) void*)g,
      (__attribute__((address_space(3))) void*)l, 16, 0, 0);
}

// ---------------- fp32 -> bf16 cast ----------------
__global__ __launch_bounds__(256) void cast_kernel(const float* __restrict__ s,
                                                   __bf16* __restrict__ d, int n4) {
  int i = blockIdx.x * blockDim.x + threadIdx.x;
  int stride = gridDim.x * blockDim.x;
  for (; i < n4; i += stride) {
    float4 v = reinterpret_cast<const float4*>(s)[i];
    bf16x4 o;
    o[0] = (__bf16)v.x; o[1] = (__bf16)v.y; o[2] = (__bf16)v.z; o[3] = (__bf16)v.w;
    reinterpret_cast<bf16x4*>(d)[i] = o;
  }
}

// ---------------- bias transpose: dst[k][q] = (bf16)src[q][k] ----------------
__global__ __launch_bounds__(256) void transpose_bias(const float* __restrict__ src,
                                                      __bf16* __restrict__ dst) {
  __shared__ float tile[64][65];
  const int bx = blockIdx.x & 15;   // col tile
  const int by = blockIdx.x >> 4;   // row tile
  const int t = threadIdx.x;
  const int lx = t & 63, ly = t >> 6;
#pragma unroll
  for (int i = 0; i < 16; ++i) {
    int row = (ly << 4) + i;
    tile[row][lx] = src[(size_t)(by * 64 + row) * 1024 + bx * 64 + lx];
  }
  __syncthreads();
#pragma unroll
  for (int i = 0; i < 16; ++i) {
    int row = (ly << 4) + i;
    dst[(size_t)(bx * 64 + row) * 1024 + by * 64 + lx] = (__bf16)tile[lx][row];
  }
}

// ======== 256x256 8-wave multi-phase bf16 GEMM: C = A(MxK)*B(NxK)^T + bias ========
// EPI: 0 = bf16, 1 = bf16 relu, 2 = f32, 3 = bf16 transposed-per-group (VT)
template <int EPI>
__global__ __launch_bounds__(512, 2) void gemm_bt(
    const __bf16* __restrict__ A, const __bf16* __restrict__ Bw,
    const float* __restrict__ bvec, __bf16* __restrict__ Cb,
    float* __restrict__ Cf, int M, int N, int K) {
  // LDS: [buf(2)][A(0)/B(1)][half(2)][128 rows][128 bytes], XOR-16B row swizzle
  __shared__ __align__(16) char sm[131072];

  const int ntn = N >> 8;
  const int nwg = gridDim.x;
  const int bid = blockIdx.x;
  const int b = (bid & 7) * (nwg >> 3) + (bid >> 3);  // bijective XCD swizzle (nwg%8==0)
  const int tm = b / ntn, tn = b % ntn;
  const int t = threadIdx.x, lane = t & 63;
  const int w = t >> 6;
  const int wm = w >> 2, wn = w & 3;          // 2 x 4 wave grid
  const int l15 = lane & 15, lq = lane >> 4;

  f32x4 acc[8][4] = {};  // [mf][nf] per-wave 128x64

  // staging geometry: thread t covers 16B at half-tile linear offsets t*16 and t*16+8192
  const int r0 = t >> 3;              // row 0..63
  const int r1 = r0 + 64;             // row 64..127
  const int kb0 = (((t & 7) << 4) ^ ((r0 & 7) << 4));  // inverse-swizzled k-byte (r1&7==r0&7)
  const int wbase = w << 10;          // wave-uniform LDS chunk base

  auto stage = [&](int kt, int p) {
    char* base = sm + (p << 16);
    const size_t kofs = (size_t)(kb0 >> 1) + ((size_t)kt << 6);
#pragma unroll
    for (int h = 0; h < 2; ++h) {
      const __bf16* gA = A + (size_t)((tm << 8) + (h << 7) + r0) * K + kofs;
      const __bf16* gA2 = A + (size_t)((tm << 8) + (h << 7) + r1) * K + kofs;
      char* lA = base + (h << 14) + wbase;
      load_lds16(gA, lA);
      load_lds16(gA2, lA + 8192);
      const __bf16* gB = Bw + (size_t)((tn << 8) + (h << 7) + r0) * K + kofs;
      const __bf16* gB2 = Bw + (size_t)((tn << 8) + (h << 7) + r1) * K + kofs;
      char* lB = base + 32768 + (h << 14) + wbase;
      load_lds16(gB, lB);
      load_lds16(gB2, lB + 8192);
    }
  };

  // prologue: stage tile 0 into buf 0
  stage(0, 0);
  asm volatile("s_waitcnt vmcnt(0)" ::: "memory");
  __builtin_amdgcn_s_barrier();

  const int NT = K >> 6;
  const int rbB = (wn & 1) << 6;
  for (int kt = 0; kt < NT; ++kt) {
    const int p = kt & 1;
    const char* Ab = sm + (p << 16) + (wm << 14);
    const char* Bb = sm + (p << 16) + 32768 + ((wn >> 1) << 14);
#pragma unroll
    for (int q = 0; q < 4; ++q) {
      bf16x8 af[2][2], bfv[4][2];
#pragma unroll
      for (int dm = 0; dm < 2; ++dm) {
        const int r = (((q << 1) + dm) << 4) + l15;
        const int sw = (r & 7) << 4;
#pragma unroll
        for (int ks = 0; ks < 2; ++ks) {
          const int lb = (ks << 6) + (lq << 4);
          af[dm][ks] = *(const bf16x8*)(Ab + r * 128 + (lb ^ sw));
        }
      }
#pragma unroll
      for (int nf = 0; nf < 4; ++nf) {
        const int r = rbB + (nf << 4) + l15;
        const int sw = (r & 7) << 4;
#pragma unroll
        for (int ks = 0; ks < 2; ++ks) {
          const int lb = (ks << 6) + (lq << 4);
          bfv[nf][ks] = *(const bf16x8*)(Bb + r * 128 + (lb ^ sw));
        }
      }
      if (q == 0 && kt + 1 < NT) stage(kt + 1, p ^ 1);
      __builtin_amdgcn_sched_barrier(0);
      __builtin_amdgcn_s_barrier();
      asm volatile("s_waitcnt lgkmcnt(0)" ::: "memory");
      __builtin_amdgcn_sched_barrier(0);
      __builtin_amdgcn_s_setprio(1);
#pragma unroll
      for (int ks = 0; ks < 2; ++ks)
#pragma unroll
        for (int dm = 0; dm < 2; ++dm)
#pragma unroll
          for (int nf = 0; nf < 4; ++nf)
            acc[(q << 1) + dm][nf] = __builtin_amdgcn_mfma_f32_16x16x32_bf16(
                af[dm][ks], bfv[nf][ks], acc[(q << 1) + dm][nf], 0, 0, 0);
      __builtin_amdgcn_s_setprio(0);
      __builtin_amdgcn_sched_barrier(0);
      if (q == 3) asm volatile("s_waitcnt vmcnt(0)" ::: "memory");
      __builtin_amdgcn_s_barrier();
    }
  }

  // epilogue: D row=(lane>>4)*4+reg, col=lane&15
  const int row0 = (tm << 8) + (wm << 7) + (lq << 2);
  const int col0 = (tn << 8) + (wn << 6) + l15;
#pragma unroll
  for (int nf = 0; nf < 4; ++nf) {
    const int col = col0 + (nf << 4);
    const float bv = bvec[col];
#pragma unroll
    for (int mf = 0; mf < 8; ++mf) {
#pragma unroll
      for (int r = 0; r < 4; ++r) {
        const int row = row0 + (mf << 4) + r;
        float v = acc[mf][nf][r] + bv;
        if (EPI == 1) v = fmaxf(v, 0.f);
        if (EPI == 2) {
          Cf[(size_t)row * N + col] = v;
        } else if (EPI == 3) {
          // VT[g=row>>7][dh=col&127][s'=(row&127)*8 + (col>>7)]
          size_t vt = ((size_t)(row >> 7) << 17) + ((size_t)(col & 127) << 10) +
                      ((row & 127) << 3) + (col >> 7);
          Cb[vt] = (__bf16)v;
        } else {
          Cb[(size_t)row * N + col] = (__bf16)v;
        }
      }
    }
  }
}

// ---------------- flash attention over flat groups ----------------
// Q,K viewed as [128][1024][128]; VT as [128][128 e][1024 k]; biasT[k][q] bf16.
// Swapped QK^T: S^T = mfma(K, Q) so each lane owns one q-row (q = lane&15).
__global__ __launch_bounds__(256) void attn_flash(
    const __bf16* __restrict__ Q, const __bf16* __restrict__ K,
    const __bf16* __restrict__ VT, const __bf16* __restrict__ biasT,
    __bf16* __restrict__ ctx) {
  __shared__ __bf16 Qs[64 * 128];    // rows 256B, swizzled
  __shared__ __bf16 Ks[64 * 128];    // rows 256B, swizzled
  __shared__ __bf16 VTs[128 * 64];   // [e][k-chunk] rows 128B, swizzled
  __shared__ __bf16 Ps[4][16 * 64];  // per-wave P tile, rows 128B, swizzled

  const int bid = blockIdx.x;
  const int b = ((bid & 7) << 8) | (bid >> 3);
  const int g = b >> 4;
  const int q0 = (b & 15) << 6;
  const size_t goff = (size_t)g << 17;
  const __bf16* Qg = Q + goff;
  const __bf16* Kg = K + goff;
  const __bf16* VTg = VT + goff;

  const int t = threadIdx.x, w = t >> 6, lane = t & 63;
  const int l15 = lane & 15, lq = lane >> 4;

  // stage Q once (chunks of 1KB = 4 rows of 256B)
  {
    int srow = lane >> 4;
    int sbo = (lane & 15) << 4;
#pragma unroll
    for (int i = 0; i < 4; ++i) {
      int c = (w << 2) + i;
      int r = (c << 2) + srow;
      int ke = (sbo ^ ((r & 7) << 4)) >> 1;
      load_lds16(Qg + (size_t)(q0 + r) * 128 + ke, (char*)Qs + (c << 10));
    }
  }

  float mrun = -INFINITY, lrun = 0.f;
  f32x4 cacc[8] = {};
  bf16x8 qf[4];
  const int qg = q0 + (w << 4) + l15;
  const int ra = (w << 4) + l15;

  for (int kb = 0; kb < 1024; kb += 64) {
    {
      int srow = lane >> 4;
      int sbo = (lane & 15) << 4;
#pragma unroll
      for (int i = 0; i < 4; ++i) {
        int c = (w << 2) + i;
        int r = (c << 2) + srow;
        int ke = (sbo ^ ((r & 7) << 4)) >> 1;
        load_lds16(Kg + (size_t)(kb + r) * 128 + ke, (char*)Ks + (c << 10));
      }
    }
    {
      int srow = lane >> 3;
      int sbo = (lane & 7) << 4;
#pragma unroll
      for (int i = 0; i < 4; ++i) {
        int c = (w << 2) + i;
        int e = (c << 3) + srow;
        int ke = kb + ((sbo ^ ((e & 7) << 4)) >> 1);
        load_lds16(VTg + (size_t)e * 1024 + ke, (char*)VTs + (c << 10));
      }
    }
    __syncthreads();

    if (kb == 0) {
#pragma unroll
      for (int ec = 0; ec < 4; ++ec) {
        int lb = (ec << 6) + (lq << 4);
        qf[ec] = *(const bf16x8*)((const char*)Qs + ra * 256 + (lb ^ ((ra & 7) << 4)));
      }
    }

    f32x4 sacc[4] = {};
#pragma unroll
    for (int ec = 0; ec < 4; ++ec) {
      const int lb = (ec << 6) + (lq << 4);
#pragma unroll
      for (int kn = 0; kn < 4; ++kn) {
        int rb = (kn << 4) + l15;
        bf16x8 kf = *(const bf16x8*)((const char*)Ks + rb * 256 + (lb ^ ((rb & 7) << 4)));
        sacc[kn] = __builtin_amdgcn_mfma_f32_16x16x32_bf16(kf, qf[ec], sacc[kn], 0, 0, 0);
      }
    }

    float sv[4][4];
#pragma unroll
    for (int kn = 0; kn < 4; ++kn) {
      int kbase = kb + (kn << 4) + (lq << 2);
#pragma unroll
      for (int r = 0; r < 4; ++r)
        sv[kn][r] = (sacc[kn][r] + (float)biasT[((size_t)(kbase + r) << 10) + qg]) * SCALE;
    }
    float mt = sv[0][0];
#pragma unroll
    for (int kn = 0; kn < 4; ++kn)
#pragma unroll
      for (int r = 0; r < 4; ++r) mt = fmaxf(mt, sv[kn][r]);
    mt = fmaxf(mt, __shfl_xor(mt, 16));
    mt = fmaxf(mt, __shfl_xor(mt, 32));
    float mnew = fmaxf(mrun, mt);
    float alpha = __expf(mrun - mnew);
    mrun = mnew;
    float psum = 0.f;
#pragma unroll
    for (int kn = 0; kn < 4; ++kn)
#pragma unroll
      for (int r = 0; r < 4; ++r) {
        float p = __expf(sv[kn][r] - mnew);
        sv[kn][r] = p;
        psum += p;
      }
    psum += __shfl_xor(psum, 16);
    psum += __shfl_xor(psum, 32);
    lrun = lrun * alpha + psum;

    float alphaR[4];
#pragma unroll
    for (int r = 0; r < 4; ++r)
      alphaR[r] = __shfl(alpha, (lane & 48) + ((lane & 48) >> 2) + r);
#pragma unroll
    for (int et = 0; et < 8; ++et)
#pragma unroll
      for (int r = 0; r < 4; ++r) cacc[et][r] *= alphaR[r];

#pragma unroll
    for (int kn = 0; kn < 4; ++kn) {
      bf16x4 pk;
      pk[0] = (__bf16)sv[kn][0]; pk[1] = (__bf16)sv[kn][1];
      pk[2] = (__bf16)sv[kn][2]; pk[3] = (__bf16)sv[kn][3];
      int bo = (kn << 5) + (lq << 3);
      *(bf16x4*)((char*)Ps[w] + l15 * 128 + (bo ^ ((l15 & 7) << 4))) = pk;
    }
    asm volatile("s_waitcnt lgkmcnt(0)" ::: "memory");
    __builtin_amdgcn_sched_barrier(0);

#pragma unroll
    for (int ks = 0; ks < 2; ++ks) {
      const int lb = (ks << 6) + (lq << 4);
      bf16x8 paf = *(const bf16x8*)((const char*)Ps[w] + l15 * 128 + (lb ^ ((l15 & 7) << 4)));
#pragma unroll
      for (int et = 0; et < 8; ++et) {
        int e = (et << 4) + l15;
        bf16x8 vf = *(const bf16x8*)((const char*)VTs + e * 128 + (lb ^ ((e & 7) << 4)));
        cacc[et] = __builtin_amdgcn_mfma_f32_16x16x32_bf16(paf, vf, cacc[et], 0, 0, 0);
      }
    }
    __syncthreads();
  }

  float lrunR[4];
#pragma unroll
  for (int r = 0; r < 4; ++r)
    lrunR[r] = __shfl(lrun, (lane & 48) + ((lane & 48) >> 2) + r);
  __bf16* cg = ctx + goff;
  const int qr = q0 + (w << 4) + (lq << 2);
#pragma unroll
  for (int et = 0; et < 8; ++et)
#pragma unroll
    for (int r = 0; r < 4; ++r) {
      float v = cacc[et][r] / lrunR[r];
      cg[(size_t)(qr + r) * 128 + (et << 4) + l15] = (__bf16)v;
    }
}

// ---------------- attn[0] full softmax matrix (group 0) ----------------
__global__ __launch_bounds__(256) void attn_head0(
    const __bf16* __restrict__ Q, const __bf16* __restrict__ K,
    const float* __restrict__ bias, float* __restrict__ out) {
  __shared__ float qrow[128];
  __shared__ float red[8];
  const int q = blockIdx.x, t = threadIdx.x;
  if (t < 128) qrow[t] = (float)Q[(size_t)q * 128 + t];
  __syncthreads();
  float s[4];
#pragma unroll
  for (int c = 0; c < 4; ++c) {
    int kc = (c << 8) + t;
    const __bf16* kr = K + (size_t)kc * 128;
    float dot = 0.f;
#pragma unroll
    for (int e = 0; e < 128; e += 8) {
      bf16x8 kv = *(const bf16x8*)(kr + e);
#pragma unroll
      for (int j = 0; j < 8; ++j) dot += qrow[e + j] * (float)kv[j];
    }
    s[c] = (dot + bias[(size_t)q * 1024 + kc]) * SCALE;
  }
  float mx = fmaxf(fmaxf(s[0], s[1]), fmaxf(s[2], s[3]));
#pragma unroll
  for (int d = 32; d >= 1; d >>= 1) mx = fmaxf(mx, __shfl_xor(mx, d));
  const int w = t >> 6, lane = t & 63;
  if (lane == 0) red[w] = mx;
  __syncthreads();
  mx = fmaxf(fmaxf(red[0], red[1]), fmaxf(red[2], red[3]));
  float ex[4], sum = 0.f;
#pragma unroll
  for (int c = 0; c < 4; ++c) { ex[c] = __expf(s[c] - mx); sum += ex[c]; }
#pragma unroll
  for (int d = 32; d >= 1; d >>= 1) sum += __shfl_xor(sum, d);
  __syncthreads();
  if (lane == 0) red[4 + w] = sum;
  __syncthreads();
  sum = red[4] + red[5] + red[6] + red[7];
  float inv = 1.f / sum;
#pragma unroll
  for (int c = 0; c < 4; ++c) out[(size_t)q * 1024 + (c << 8) + t] = ex[c] * inv;
}

// ---------------- LayerNorm(a + b) * g + beta ----------------
template <int B_BF16>
__global__ __launch_bounds__(256) void ln_res(
    const float* __restrict__ a, const void* __restrict__ bptr,
    const float* __restrict__ gam, const float* __restrict__ bet,
    float* __restrict__ outf, __bf16* __restrict__ outb) {
  __shared__ float red[8];
  const int row = blockIdx.x, t = threadIdx.x;
  const size_t base = (size_t)row << 10;
  float4 va = reinterpret_cast<const float4*>(a + base)[t];
  float b0, b1, b2, b3;
  if (B_BF16) {
    bf16x4 vb = reinterpret_cast<const bf16x4*>((const __bf16*)bptr + base)[t];
    b0 = (float)vb[0]; b1 = (float)vb[1]; b2 = (float)vb[2]; b3 = (float)vb[3];
  } else {
    float4 vb = reinterpret_cast<const float4*>((const float*)bptr + base)[t];
    b0 = vb.x; b1 = vb.y; b2 = vb.z; b3 = vb.w;
  }
  float v0 = va.x + b0, v1 = va.y + b1, v2 = va.z + b2, v3 = va.w + b3;
  float s = v0 + v1 + v2 + v3;
  float qq = v0 * v0 + v1 * v1 + v2 * v2 + v3 * v3;
#pragma unroll
  for (int d = 32; d >= 1; d >>= 1) {
    s += __shfl_xor(s, d);
    qq += __shfl_xor(qq, d);
  }
  const int w = t >> 6, lane = t & 63;
  if (lane == 0) { red[w] = s; red[4 + w] = qq; }
  __syncthreads();
  s = red[0] + red[1] + red[2] + red[3];
  qq = red[4] + red[5] + red[6] + red[7];
  const float mu = s * (1.f / 1024.f);
  const float var = qq * (1.f / 1024.f) - mu * mu;
  const float rs = rsqrtf(var + 1e-5f);
  float4 g4 = reinterpret_cast<const float4*>(gam)[t];
  float4 b4 = reinterpret_cast<const float4*>(bet)[t];
  float o0 = (v0 - mu) * rs * g4.x + b4.x;
  float o1 = (v1 - mu) * rs * g4.y + b4.y;
  float o2 = (v2 - mu) * rs * g4.z + b4.z;
  float o3 = (v3 - mu) * rs * g4.w + b4.w;
  if (outf) reinterpret_cast<float4*>(outf + base)[t] = make_float4(o0, o1, o2, o3);
  if (outb) {
    bf16x4 ob;
    ob[0] = (__bf16)o0; ob[1] = (__bf16)o1; ob[2] = (__bf16)o2; ob[3] = (__bf16)o3;
    reinterpret_cast<bf16x4*>(outb + base)[t] = ob;
  }
}

extern "C" void kernel_launch(void* const* d_in, const int* in_sizes, int n_in,
                              void* d_out, int out_size, void* d_ws, size_t ws_size,
                              hipStream_t stream) {
  (void)in_sizes; (void)n_in; (void)out_size; (void)ws_size;
  const float* x    = (const float*)d_in[0];
  const float* bias = (const float*)d_in[1];
  const float* Wq   = (const float*)d_in[2];
  const float* bq   = (const float*)d_in[3];
  const float* Wk   = (const float*)d_in[4];
  const float* bk   = (const float*)d_in[5];
  const float* Wv   = (const float*)d_in[6];
  const float* bv   = (const float*)d_in[7];
  const float* Wo   = (const float*)d_in[8];
  const float* bo   = (const float*)d_in[9];
  const float* g1   = (const float*)d_in[10];
  const float* b1l  = (const float*)d_in[11];
  const float* W1   = (const float*)d_in[12];
  const float* b1f  = (const float*)d_in[13];
  const float* W2   = (const float*)d_in[14];
  const float* b2f  = (const float*)d_in[15];
  const float* g2   = (const float*)d_in[16];
  const float* b2l  = (const float*)d_in[17];

  // ---- workspace layout (~186 MB) ----
  char* ws = (char*)d_ws;
  size_t off = 0;
  auto alloc = [&](size_t bytes) {
    char* p = ws + off;
    off += (bytes + 255) & ~(size_t)255;
    return p;
  };
  __bf16* wqb  = (__bf16*)alloc(2097152);
  __bf16* wkb  = (__bf16*)alloc(2097152);
  __bf16* wvb  = (__bf16*)alloc(2097152);
  __bf16* wob  = (__bf16*)alloc(2097152);
  __bf16* w1b  = (__bf16*)alloc(8388608);
  __bf16* w2b  = (__bf16*)alloc(8388608);
  __bf16* biasTb = (__bf16*)alloc(2097152);       // bias^T bf16 [k][q]
  __bf16* xb   = (__bf16*)alloc(33554432);        // x bf16; later res1 bf16
  __bf16* Qb   = (__bf16*)alloc(4ull * 33554432); // Q,K,VT,ctx; later h [16384,4096]
  __bf16* Kb   = Qb + 16777216;
  __bf16* VTb  = Kb + 16777216;                   // V stored transposed per group
  __bf16* ctxb = VTb + 16777216;
  __bf16* hb   = Qb;
  __bf16* res1b = xb;

  // d_out doubles as f32 scratch for attn_out / ff (out2 slot, overwritten at end)
  float* out2     = (float*)d_out;
  float* selfattn = (float*)d_out + 16777216;
  float* attn_out = out2;
  float* ff       = out2;

  // casts + bias transpose
  cast_kernel<<<2048, 256, 0, stream>>>(x, xb, 16777216 / 4);
  cast_kernel<<<1024, 256, 0, stream>>>(Wq, wqb, 1048576 / 4);
  cast_kernel<<<1024, 256, 0, stream>>>(Wk, wkb, 1048576 / 4);
  cast_kernel<<<1024, 256, 0, stream>>>(Wv, wvb, 1048576 / 4);
  cast_kernel<<<1024, 256, 0, stream>>>(Wo, wob, 1048576 / 4);
  cast_kernel<<<1024, 256, 0, stream>>>(W1, w1b, 4194304 / 4);
  cast_kernel<<<1024, 256, 0, stream>>>(W2, w2b, 4194304 / 4);
  transpose_bias<<<256, 256, 0, stream>>>(bias, biasTb);

  // QKV projections (V written pre-transposed per group); 256x256 tiles, 512 thr
  gemm_bt<0><<<64 * 4, 512, 0, stream>>>(xb, wqb, bq, Qb, nullptr, 16384, 1024, 1024);
  gemm_bt<0><<<64 * 4, 512, 0, stream>>>(xb, wkb, bk, Kb, nullptr, 16384, 1024, 1024);
  gemm_bt<3><<<64 * 4, 512, 0, stream>>>(xb, wvb, bv, VTb, nullptr, 16384, 1024, 1024);

  // attention
  attn_head0<<<1024, 256, 0, stream>>>(Qb, Kb, bias, selfattn);
  attn_flash<<<128 * 16, 256, 0, stream>>>(Qb, Kb, VTb, biasTb, ctxb);

  // output projection -> f32 scratch in d_out
  gemm_bt<2><<<64 * 4, 512, 0, stream>>>(ctxb, wob, bo, nullptr, attn_out, 16384, 1024, 1024);

  // ln1(attn_out + x) -> res1 bf16 (xb slot)
  ln_res<0><<<16384, 256, 0, stream>>>(attn_out, x, g1, b1l, nullptr, res1b);

  // FFN
  gemm_bt<1><<<64 * 16, 512, 0, stream>>>(res1b, w1b, b1f, hb, nullptr, 16384, 4096, 1024);
  gemm_bt<2><<<64 * 4, 512, 0, stream>>>(hb, w2b, b2f, nullptr, ff, 16384, 1024, 4096);

  // ln2(ff + res1) -> out2 (in-place over ff)
  ln_res<1><<<16384, 256, 0, stream>>>(ff, res1b, g2, b2l, out2, nullptr);
}

// Round 5
// 773.167 us; speedup vs baseline: 1.2094x; 1.1232x over previous
//
#include <hip/hip_runtime.h>
#include <hip/hip_bf16.h>
#include <math.h>

typedef __attribute__((ext_vector_type(4))) float f32x4;
typedef __attribute__((ext_vector_type(8))) __bf16 bf16x8;
typedef __attribute__((ext_vector_type(4))) __bf16 bf16x4;

static constexpr float SCALE = 0.08838834764831845f; // 128^-0.5

__device__ __forceinline__ void load_lds16(const void* g, void* l) {
  __builtin_amdgcn_global_load_lds(
      (const __attribute__((address_space(1))) void*)g,
      (__attribute__((address_space(3))) void*)l, 16, 0, 0);
}

// ---------------- fp32 -> bf16 cast ----------------
__global__ __launch_bounds__(256) void cast_kernel(const float* __restrict__ s,
                                                   __bf16* __restrict__ d, int n4) {
  int i = blockIdx.x * blockDim.x + threadIdx.x;
  int stride = gridDim.x * blockDim.x;
  for (; i < n4; i += stride) {
    float4 v = reinterpret_cast<const float4*>(s)[i];
    bf16x4 o;
    o[0] = (__bf16)v.x; o[1] = (__bf16)v.y; o[2] = (__bf16)v.z; o[3] = (__bf16)v.w;
    reinterpret_cast<bf16x4*>(d)[i] = o;
  }
}

// ---------------- bias transpose: dst[k][q] = (bf16)src[q][k] ----------------
__global__ __launch_bounds__(256) void transpose_bias(const float* __restrict__ src,
                                                      __bf16* __restrict__ dst) {
  __shared__ float tile[64][65];
  const int bx = blockIdx.x & 15;   // col tile
  const int by = blockIdx.x >> 4;   // row tile
  const int t = threadIdx.x;
  const int lx = t & 63, ly = t >> 6;
#pragma unroll
  for (int i = 0; i < 16; ++i) {
    int row = (ly << 4) + i;
    tile[row][lx] = src[(size_t)(by * 64 + row) * 1024 + bx * 64 + lx];
  }
  __syncthreads();
#pragma unroll
  for (int i = 0; i < 16; ++i) {
    int row = (ly << 4) + i;
    dst[(size_t)(bx * 64 + row) * 1024 + by * 64 + lx] = (__bf16)tile[lx][row];
  }
}

// ======== 256x256 8-wave bf16 GEMM, dbuf + full-tile-cover drain ========
// C = A(MxK) * B(NxK)^T + bias
// EPI: 0 = bf16, 1 = bf16 relu, 2 = f32, 3 = bf16 transposed-per-group (VT)
template <int EPI>
__global__ __launch_bounds__(512, 2) void gemm_bt(
    const __bf16* __restrict__ A, const __bf16* __restrict__ Bw,
    const float* __restrict__ bvec, __bf16* __restrict__ Cb,
    float* __restrict__ Cf, int M, int N, int K) {
  // LDS: [buf(2)][A(0)/B(1)][half(2)][128 rows][128 bytes], XOR-16B row swizzle
  __shared__ __align__(16) char sm[131072];

  const int ntn = N >> 8;
  const int nwg = gridDim.x;
  const int bid = blockIdx.x;
  const int b = (bid & 7) * (nwg >> 3) + (bid >> 3);  // bijective XCD swizzle (nwg%8==0)
  const int tm = b / ntn, tn = b % ntn;
  const int t = threadIdx.x, lane = t & 63;
  const int w = t >> 6;
  const int wm = w >> 2, wn = w & 3;          // 2 x 4 wave grid
  const int l15 = lane & 15, lq = lane >> 4;

  f32x4 acc[8][4] = {};  // [mf][nf] per-wave 128x64

  // staging geometry: thread t covers 16B at half-tile linear offsets t*16 and t*16+8192
  const int r0 = t >> 3;              // row 0..63
  const int r1 = r0 + 64;             // row 64..127
  const int kb0 = (((t & 7) << 4) ^ ((r0 & 7) << 4));  // inverse-swizzled k-byte (r1&7==r0&7)
  const int wbase = w << 10;          // wave-uniform LDS chunk base

  auto stage = [&](int kt, int p) {
    char* base = sm + (p << 16);
    const size_t kofs = (size_t)(kb0 >> 1) + ((size_t)kt << 6);
#pragma unroll
    for (int h = 0; h < 2; ++h) {
      const __bf16* gA = A + (size_t)((tm << 8) + (h << 7) + r0) * K + kofs;
      const __bf16* gA2 = A + (size_t)((tm << 8) + (h << 7) + r1) * K + kofs;
      char* lA = base + (h << 14) + wbase;
      load_lds16(gA, lA);
      load_lds16(gA2, lA + 8192);
      const __bf16* gB = Bw + (size_t)((tn << 8) + (h << 7) + r0) * K + kofs;
      const __bf16* gB2 = Bw + (size_t)((tn << 8) + (h << 7) + r1) * K + kofs;
      char* lB = base + 32768 + (h << 14) + wbase;
      load_lds16(gB, lB);
      load_lds16(gB2, lB + 8192);
    }
  };

  // prologue: stage tile 0 into buf 0
  stage(0, 0);
  __syncthreads();

  const int NT = K >> 6;
  const int rbB = (wn & 1) << 6;
  for (int kt = 0; kt < NT; ++kt) {
    const int p = kt & 1;
    const char* Ab = sm + (p << 16) + (wm << 14);
    const char* Bb = sm + (p << 16) + 32768 + ((wn >> 1) << 14);
    // prefetch next tile into the other buffer; drained by the tile-end
    // __syncthreads -> cover = this whole tile's ds_reads + 64 MFMA
    if (kt + 1 < NT) stage(kt + 1, p ^ 1);

    // hoist all 8 B-frags for this tile (registers), read once
    bf16x8 bfv[4][2];
#pragma unroll
    for (int nf = 0; nf < 4; ++nf) {
      const int r = rbB + (nf << 4) + l15;
      const int sw = (r & 7) << 4;
#pragma unroll
      for (int ks = 0; ks < 2; ++ks) {
        const int lb = (ks << 6) + (lq << 4);
        bfv[nf][ks] = *(const bf16x8*)(Bb + r * 128 + (lb ^ sw));
      }
    }
    // 4 sub-phases over M; no intra-tile barriers — compiler interleaves
    // ds_reads with MFMA via fine-grained lgkmcnt
#pragma unroll
    for (int q = 0; q < 4; ++q) {
      bf16x8 af[2][2];
#pragma unroll
      for (int dm = 0; dm < 2; ++dm) {
        const int r = (((q << 1) + dm) << 4) + l15;
        const int sw = (r & 7) << 4;
#pragma unroll
        for (int ks = 0; ks < 2; ++ks) {
          const int lb = (ks << 6) + (lq << 4);
          af[dm][ks] = *(const bf16x8*)(Ab + r * 128 + (lb ^ sw));
        }
      }
#pragma unroll
      for (int ks = 0; ks < 2; ++ks)
#pragma unroll
        for (int dm = 0; dm < 2; ++dm)
#pragma unroll
          for (int nf = 0; nf < 4; ++nf)
            acc[(q << 1) + dm][nf] = __builtin_amdgcn_mfma_f32_16x16x32_bf16(
                af[dm][ks], bfv[nf][ks], acc[(q << 1) + dm][nf], 0, 0, 0);
    }
    __syncthreads();
  }

  // epilogue: D row=(lane>>4)*4+reg, col=lane&15
  const int row0 = (tm << 8) + (wm << 7) + (lq << 2);
  const int col0 = (tn << 8) + (wn << 6) + l15;
#pragma unroll
  for (int nf = 0; nf < 4; ++nf) {
    const int col = col0 + (nf << 4);
    const float bv = bvec[col];
#pragma unroll
    for (int mf = 0; mf < 8; ++mf) {
#pragma unroll
      for (int r = 0; r < 4; ++r) {
        const int row = row0 + (mf << 4) + r;
        float v = acc[mf][nf][r] + bv;
        if (EPI == 1) v = fmaxf(v, 0.f);
        if (EPI == 2) {
          Cf[(size_t)row * N + col] = v;
        } else if (EPI == 3) {
          // VT[g=row>>7][dh=col&127][s'=(row&127)*8 + (col>>7)]
          size_t vt = ((size_t)(row >> 7) << 17) + ((size_t)(col & 127) << 10) +
                      ((row & 127) << 3) + (col >> 7);
          Cb[vt] = (__bf16)v;
        } else {
          Cb[(size_t)row * N + col] = (__bf16)v;
        }
      }
    }
  }
}

// ---------------- flash attention over flat groups ----------------
// Q,K viewed as [128][1024][128]; VT as [128][128 e][1024 k]; biasT[k][q] bf16.
// Swapped QK^T: S^T = mfma(K, Q) so each lane owns one q-row (q = lane&15).
__global__ __launch_bounds__(256) void attn_flash(
    const __bf16* __restrict__ Q, const __bf16* __restrict__ K,
    const __bf16* __restrict__ VT, const __bf16* __restrict__ biasT,
    __bf16* __restrict__ ctx) {
  __shared__ __bf16 Qs[64 * 128];    // rows 256B, swizzled
  __shared__ __bf16 Ks[64 * 128];    // rows 256B, swizzled
  __shared__ __bf16 VTs[128 * 64];   // [e][k-chunk] rows 128B, swizzled
  __shared__ __bf16 Ps[4][16 * 64];  // per-wave P tile, rows 128B, swizzled

  const int bid = blockIdx.x;
  const int b = ((bid & 7) << 8) | (bid >> 3);
  const int g = b >> 4;
  const int q0 = (b & 15) << 6;
  const size_t goff = (size_t)g << 17;
  const __bf16* Qg = Q + goff;
  const __bf16* Kg = K + goff;
  const __bf16* VTg = VT + goff;

  const int t = threadIdx.x, w = t >> 6, lane = t & 63;
  const int l15 = lane & 15, lq = lane >> 4;

  // stage Q once (chunks of 1KB = 4 rows of 256B)
  {
    int srow = lane >> 4;
    int sbo = (lane & 15) << 4;
#pragma unroll
    for (int i = 0; i < 4; ++i) {
      int c = (w << 2) + i;
      int r = (c << 2) + srow;
      int ke = (sbo ^ ((r & 7) << 4)) >> 1;
      load_lds16(Qg + (size_t)(q0 + r) * 128 + ke, (char*)Qs + (c << 10));
    }
  }

  float mrun = -INFINITY, lrun = 0.f;
  f32x4 cacc[8] = {};
  bf16x8 qf[4];
  const int qg = q0 + (w << 4) + l15;
  const int ra = (w << 4) + l15;

  for (int kb = 0; kb < 1024; kb += 64) {
    {
      int srow = lane >> 4;
      int sbo = (lane & 15) << 4;
#pragma unroll
      for (int i = 0; i < 4; ++i) {
        int c = (w << 2) + i;
        int r = (c << 2) + srow;
        int ke = (sbo ^ ((r & 7) << 4)) >> 1;
        load_lds16(Kg + (size_t)(kb + r) * 128 + ke, (char*)Ks + (c << 10));
      }
    }
    {
      int srow = lane >> 3;
      int sbo = (lane & 7) << 4;
#pragma unroll
      for (int i = 0; i < 4; ++i) {
        int c = (w << 2) + i;
        int e = (c << 3) + srow;
        int ke = kb + ((sbo ^ ((e & 7) << 4)) >> 1);
        load_lds16(VTg + (size_t)e * 1024 + ke, (char*)VTs + (c << 10));
      }
    }
    __syncthreads();

    if (kb == 0) {
#pragma unroll
      for (int ec = 0; ec < 4; ++ec) {
        int lb = (ec << 6) + (lq << 4);
        qf[ec] = *(const bf16x8*)((const char*)Qs + ra * 256 + (lb ^ ((ra & 7) << 4)));
      }
    }

    f32x4 sacc[4] = {};
#pragma unroll
    for (int ec = 0; ec < 4; ++ec) {
      const int lb = (ec << 6) + (lq << 4);
#pragma unroll
      for (int kn = 0; kn < 4; ++kn) {
        int rb = (kn << 4) + l15;
        bf16x8 kf = *(const bf16x8*)((const char*)Ks + rb * 256 + (lb ^ ((rb & 7) << 4)));
        sacc[kn] = __builtin_amdgcn_mfma_f32_16x16x32_bf16(kf, qf[ec], sacc[kn], 0, 0, 0);
      }
    }

    float sv[4][4];
#pragma unroll
    for (int kn = 0; kn < 4; ++kn) {
      int kbase = kb + (kn << 4) + (lq << 2);
#pragma unroll
      for (int r = 0; r < 4; ++r)
        sv[kn][r] = (sacc[kn][r] + (float)biasT[((size_t)(kbase + r) << 10) + qg]) * SCALE;
    }
    float mt = sv[0][0];
#pragma unroll
    for (int kn = 0; kn < 4; ++kn)
#pragma unroll
      for (int r = 0; r < 4; ++r) mt = fmaxf(mt, sv[kn][r]);
    mt = fmaxf(mt, __shfl_xor(mt, 16));
    mt = fmaxf(mt, __shfl_xor(mt, 32));
    float mnew = fmaxf(mrun, mt);
    float alpha = __expf(mrun - mnew);
    mrun = mnew;
    float psum = 0.f;
#pragma unroll
    for (int kn = 0; kn < 4; ++kn)
#pragma unroll
      for (int r = 0; r < 4; ++r) {
        float p = __expf(sv[kn][r] - mnew);
        sv[kn][r] = p;
        psum += p;
      }
    psum += __shfl_xor(psum, 16);
    psum += __shfl_xor(psum, 32);
    lrun = lrun * alpha + psum;

    float alphaR[4];
#pragma unroll
    for (int r = 0; r < 4; ++r)
      alphaR[r] = __shfl(alpha, (lane & 48) + ((lane & 48) >> 2) + r);
#pragma unroll
    for (int et = 0; et < 8; ++et)
#pragma unroll
      for (int r = 0; r < 4; ++r) cacc[et][r] *= alphaR[r];

#pragma unroll
    for (int kn = 0; kn < 4; ++kn) {
      bf16x4 pk;
      pk[0] = (__bf16)sv[kn][0]; pk[1] = (__bf16)sv[kn][1];
      pk[2] = (__bf16)sv[kn][2]; pk[3] = (__bf16)sv[kn][3];
      int bo = (kn << 5) + (lq << 3);
      *(bf16x4*)((char*)Ps[w] + l15 * 128 + (bo ^ ((l15 & 7) << 4))) = pk;
    }
    asm volatile("s_waitcnt lgkmcnt(0)" ::: "memory");
    __builtin_amdgcn_sched_barrier(0);

#pragma unroll
    for (int ks = 0; ks < 2; ++ks) {
      const int lb = (ks << 6) + (lq << 4);
      bf16x8 paf = *(const bf16x8*)((const char*)Ps[w] + l15 * 128 + (lb ^ ((l15 & 7) << 4)));
#pragma unroll
      for (int et = 0; et < 8; ++et) {
        int e = (et << 4) + l15;
        bf16x8 vf = *(const bf16x8*)((const char*)VTs + e * 128 + (lb ^ ((e & 7) << 4)));
        cacc[et] = __builtin_amdgcn_mfma_f32_16x16x32_bf16(paf, vf, cacc[et], 0, 0, 0);
      }
    }
    __syncthreads();
  }

  float lrunR[4];
#pragma unroll
  for (int r = 0; r < 4; ++r)
    lrunR[r] = __shfl(lrun, (lane & 48) + ((lane & 48) >> 2) + r);
  __bf16* cg = ctx + goff;
  const int qr = q0 + (w << 4) + (lq << 2);
#pragma unroll
  for (int et = 0; et < 8; ++et)
#pragma unroll
    for (int r = 0; r < 4; ++r) {
      float v = cacc[et][r] / lrunR[r];
      cg[(size_t)(qr + r) * 128 + (et << 4) + l15] = (__bf16)v;
    }
}

// ---------------- attn[0] full softmax matrix (group 0) ----------------
__global__ __launch_bounds__(256) void attn_head0(
    const __bf16* __restrict__ Q, const __bf16* __restrict__ K,
    const float* __restrict__ bias, float* __restrict__ out) {
  __shared__ float qrow[128];
  __shared__ float red[8];
  const int q = blockIdx.x, t = threadIdx.x;
  if (t < 128) qrow[t] = (float)Q[(size_t)q * 128 + t];
  __syncthreads();
  float s[4];
#pragma unroll
  for (int c = 0; c < 4; ++c) {
    int kc = (c << 8) + t;
    const __bf16* kr = K + (size_t)kc * 128;
    float dot = 0.f;
#pragma unroll
    for (int e = 0; e < 128; e += 8) {
      bf16x8 kv = *(const bf16x8*)(kr + e);
#pragma unroll
      for (int j = 0; j < 8; ++j) dot += qrow[e + j] * (float)kv[j];
    }
    s[c] = (dot + bias[(size_t)q * 1024 + kc]) * SCALE;
  }
  float mx = fmaxf(fmaxf(s[0], s[1]), fmaxf(s[2], s[3]));
#pragma unroll
  for (int d = 32; d >= 1; d >>= 1) mx = fmaxf(mx, __shfl_xor(mx, d));
  const int w = t >> 6, lane = t & 63;
  if (lane == 0) red[w] = mx;
  __syncthreads();
  mx = fmaxf(fmaxf(red[0], red[1]), fmaxf(red[2], red[3]));
  float ex[4], sum = 0.f;
#pragma unroll
  for (int c = 0; c < 4; ++c) { ex[c] = __expf(s[c] - mx); sum += ex[c]; }
#pragma unroll
  for (int d = 32; d >= 1; d >>= 1) sum += __shfl_xor(sum, d);
  __syncthreads();
  if (lane == 0) red[4 + w] = sum;
  __syncthreads();
  sum = red[4] + red[5] + red[6] + red[7];
  float inv = 1.f / sum;
#pragma unroll
  for (int c = 0; c < 4; ++c) out[(size_t)q * 1024 + (c << 8) + t] = ex[c] * inv;
}

// ---------------- LayerNorm(a + b) * g + beta ----------------
template <int B_BF16>
__global__ __launch_bounds__(256) void ln_res(
    const float* __restrict__ a, const void* __restrict__ bptr,
    const float* __restrict__ gam, const float* __restrict__ bet,
    float* __restrict__ outf, __bf16* __restrict__ outb) {
  __shared__ float red[8];
  const int row = blockIdx.x, t = threadIdx.x;
  const size_t base = (size_t)row << 10;
  float4 va = reinterpret_cast<const float4*>(a + base)[t];
  float b0, b1, b2, b3;
  if (B_BF16) {
    bf16x4 vb = reinterpret_cast<const bf16x4*>((const __bf16*)bptr + base)[t];
    b0 = (float)vb[0]; b1 = (float)vb[1]; b2 = (float)vb[2]; b3 = (float)vb[3];
  } else {
    float4 vb = reinterpret_cast<const float4*>((const float*)bptr + base)[t];
    b0 = vb.x; b1 = vb.y; b2 = vb.z; b3 = vb.w;
  }
  float v0 = va.x + b0, v1 = va.y + b1, v2 = va.z + b2, v3 = va.w + b3;
  float s = v0 + v1 + v2 + v3;
  float qq = v0 * v0 + v1 * v1 + v2 * v2 + v3 * v3;
#pragma unroll
  for (int d = 32; d >= 1; d >>= 1) {
    s += __shfl_xor(s, d);
    qq += __shfl_xor(qq, d);
  }
  const int w = t >> 6, lane = t & 63;
  if (lane == 0) { red[w] = s; red[4 + w] = qq; }
  __syncthreads();
  s = red[0] + red[1] + red[2] + red[3];
  qq = red[4] + red[5] + red[6] + red[7];
  const float mu = s * (1.f / 1024.f);
  const float var = qq * (1.f / 1024.f) - mu * mu;
  const float rs = rsqrtf(var + 1e-5f);
  float4 g4 = reinterpret_cast<const float4*>(gam)[t];
  float4 b4 = reinterpret_cast<const float4*>(bet)[t];
  float o0 = (v0 - mu) * rs * g4.x + b4.x;
  float o1 = (v1 - mu) * rs * g4.y + b4.y;
  float o2 = (v2 - mu) * rs * g4.z + b4.z;
  float o3 = (v3 - mu) * rs * g4.w + b4.w;
  if (outf) reinterpret_cast<float4*>(outf + base)[t] = make_float4(o0, o1, o2, o3);
  if (outb) {
    bf16x4 ob;
    ob[0] = (__bf16)o0; ob[1] = (__bf16)o1; ob[2] = (__bf16)o2; ob[3] = (__bf16)o3;
    reinterpret_cast<bf16x4*>(outb + base)[t] = ob;
  }
}

extern "C" void kernel_launch(void* const* d_in, const int* in_sizes, int n_in,
                              void* d_out, int out_size, void* d_ws, size_t ws_size,
                              hipStream_t stream) {
  (void)in_sizes; (void)n_in; (void)out_size; (void)ws_size;
  const float* x    = (const float*)d_in[0];
  const float* bias = (const float*)d_in[1];
  const float* Wq   = (const float*)d_in[2];
  const float* bq   = (const float*)d_in[3];
  const float* Wk   = (const float*)d_in[4];
  const float* bk   = (const float*)d_in[5];
  const float* Wv   = (const float*)d_in[6];
  const float* bv   = (const float*)d_in[7];
  const float* Wo   = (const float*)d_in[8];
  const float* bo   = (const float*)d_in[9];
  const float* g1   = (const float*)d_in[10];
  const float* b1l  = (const float*)d_in[11];
  const float* W1   = (const float*)d_in[12];
  const float* b1f  = (const float*)d_in[13];
  const float* W2   = (const float*)d_in[14];
  const float* b2f  = (const float*)d_in[15];
  const float* g2   = (const float*)d_in[16];
  const float* b2l  = (const float*)d_in[17];

  // ---- workspace layout (~186 MB) ----
  char* ws = (char*)d_ws;
  size_t off = 0;
  auto alloc = [&](size_t bytes) {
    char* p = ws + off;
    off += (bytes + 255) & ~(size_t)255;
    return p;
  };
  __bf16* wqb  = (__bf16*)alloc(2097152);
  __bf16* wkb  = (__bf16*)alloc(2097152);
  __bf16* wvb  = (__bf16*)alloc(2097152);
  __bf16* wob  = (__bf16*)alloc(2097152);
  __bf16* w1b  = (__bf16*)alloc(8388608);
  __bf16* w2b  = (__bf16*)alloc(8388608);
  __bf16* biasTb = (__bf16*)alloc(2097152);       // bias^T bf16 [k][q]
  __bf16* xb   = (__bf16*)alloc(33554432);        // x bf16; later res1 bf16
  __bf16* Qb   = (__bf16*)alloc(4ull * 33554432); // Q,K,VT,ctx; later h [16384,4096]
  __bf16* Kb   = Qb + 16777216;
  __bf16* VTb  = Kb + 16777216;                   // V stored transposed per group
  __bf16* ctxb = VTb + 16777216;
  __bf16* hb   = Qb;
  __bf16* res1b = xb;

  // d_out doubles as f32 scratch for attn_out / ff (out2 slot, overwritten at end)
  float* out2     = (float*)d_out;
  float* selfattn = (float*)d_out + 16777216;
  float* attn_out = out2;
  float* ff       = out2;

  // casts + bias transpose
  cast_kernel<<<2048, 256, 0, stream>>>(x, xb, 16777216 / 4);
  cast_kernel<<<1024, 256, 0, stream>>>(Wq, wqb, 1048576 / 4);
  cast_kernel<<<1024, 256, 0, stream>>>(Wk, wkb, 1048576 / 4);
  cast_kernel<<<1024, 256, 0, stream>>>(Wv, wvb, 1048576 / 4);
  cast_kernel<<<1024, 256, 0, stream>>>(Wo, wob, 1048576 / 4);
  cast_kernel<<<1024, 256, 0, stream>>>(W1, w1b, 4194304 / 4);
  cast_kernel<<<1024, 256, 0, stream>>>(W2, w2b, 4194304 / 4);
  transpose_bias<<<256, 256, 0, stream>>>(bias, biasTb);

  // QKV projections (V written pre-transposed per group); 256x256 tiles, 512 thr
  gemm_bt<0><<<64 * 4, 512, 0, stream>>>(xb, wqb, bq, Qb, nullptr, 16384, 1024, 1024);
  gemm_bt<0><<<64 * 4, 512, 0, stream>>>(xb, wkb, bk, Kb, nullptr, 16384, 1024, 1024);
  gemm_bt<3><<<64 * 4, 512, 0, stream>>>(xb, wvb, bv, VTb, nullptr, 16384, 1024, 1024);

  // attention
  attn_head0<<<1024, 256, 0, stream>>>(Qb, Kb, bias, selfattn);
  attn_flash<<<128 * 16, 256, 0, stream>>>(Qb, Kb, VTb, biasTb, ctxb);

  // output projection -> f32 scratch in d_out
  gemm_bt<2><<<64 * 4, 512, 0, stream>>>(ctxb, wob, bo, nullptr, attn_out, 16384, 1024, 1024);

  // ln1(attn_out + x) -> res1 bf16 (xb slot)
  ln_res<0><<<16384, 256, 0, stream>>>(attn_out, x, g1, b1l, nullptr, res1b);

  // FFN
  gemm_bt<1><<<64 * 16, 512, 0, stream>>>(res1b, w1b, b1f, hb, nullptr, 16384, 4096, 1024);
  gemm_bt<2><<<64 * 4, 512, 0, stream>>>(hb, w2b, b2f, nullptr, ff, 16384, 1024, 4096);

  // ln2(ff + res1) -> out2 (in-place over ff)
  ln_res<1><<<16384, 256, 0, stream>>>(ff, res1b, g2, b2l, out2, nullptr);
}